// Round 16
// baseline (123.905 us; speedup 1.0000x reference)
//
#include <hip/hip_runtime.h>
#include <math.h>

// MarketRegimeHMM forward via chunked associative scan — linear semiring,
// base-2 scales.  R15 = R12 (108.4us best: bf16-packed LDS tile, row-parallel
// fold, full-chunk k_alpha) + two fixed-cost cuts:
//   1. k_prep fused into k_build (each block preps params into its own LDS;
//      raw inputs are 3KB, L2-broadcast) -> one fewer launch, no ws P region.
//   2. SoA 56-byte wsE records (e0/e1/e2 uint4 + e3 uint2, no pad words)
//      -> -8MB write, -8MB read.
//
//   k_build : 256 t per block; in-block param prep; thread t builds E_t +
//             packs 14 u32; swizzled u32 LDS tile; 8 lanes/chunk row-parallel
//             fold -> R[b][c].
//   k_scan  : one block per b; 512-record scan -> start[b][c], LL[b].
//   k_alpha : one lane per chunk: stream bf16 E, 25 FMA + 5 log2 per t.

namespace {

constexpr int kS = 5, kD = 16, kB = 256, kT = 4096;
constexpr int kC = 8, kNC = 512;     // chunks per batch element
constexpr int kTile = 256, kCPT = 32;
constexpr int kG = 16, kNG = 32;

constexpr float kL2E = 1.4426950408889634f;  // 1/ln2
constexpr float kLn2 = 0.6931471805599453f;

// LDS param layout (floats), all vector-read aligned:
constexpr int L_QA  = 0;    // 80  -0.5*inv_v/ln2           [s*16+d] float4
constexpr int L_QB  = 80;   // 80  mu*inv_v/ln2             [s*16+d] float4
constexpr int L_QC  = 160;  // 5   -0.5/ln2*(16ln2pi + sum(lv + iv*mu^2))
constexpr int L_LN  = 168;  // 5   log2_softmax(log_initial)
constexpr int L_W1H = 176;  // 100 half2 pairs of (2/ln2)*W1: [i*20 + h*2 + {01,23}]
constexpr int L_B1  = 276;  // 60  (2/ln2)*b1, rows of 12    f4,f4,f2
constexpr int L_W2H = 336;  // 200 rows of 8: [0..4]=half2 of -2*W2/ln2 pairs,
                            //     [5]=f32 (b2+tb+sum W2)/ln2, [6,7]=0
constexpr int P_TOT = 544;  // LDS floats

typedef __fp16 half2_t __attribute__((ext_vector_type(2)));

#if __has_builtin(__builtin_amdgcn_exp2f)
__device__ __forceinline__ float ex2(float x) { return __builtin_amdgcn_exp2f(x); }
#else
__device__ __forceinline__ float ex2(float x) { return exp2f(x); }
#endif
#if __has_builtin(__builtin_amdgcn_logf)
__device__ __forceinline__ float lg2(float x) { return __builtin_amdgcn_logf(x); }
#else
__device__ __forceinline__ float lg2(float x) { return __log2f(x); }
#endif

__device__ __forceinline__ unsigned pkh(float a, float b) {
  return __builtin_bit_cast(unsigned, __builtin_amdgcn_cvt_pkrtz(a, b));
}

#if __has_builtin(__builtin_amdgcn_fdot2)
__device__ __forceinline__ float fdot2u(unsigned w, unsigned x, float acc) {
  return __builtin_amdgcn_fdot2(__builtin_bit_cast(half2_t, w),
                                __builtin_bit_cast(half2_t, x), acc, false);
}
#else
__device__ __forceinline__ float fdot2u(unsigned w, unsigned x, float acc) {
  const half2_t hw = __builtin_bit_cast(half2_t, w);
  const half2_t hx = __builtin_bit_cast(half2_t, x);
  return acc + (float)hw.x * (float)hx.x + (float)hw.y * (float)hx.y;
}
#endif

__device__ __forceinline__ float max5(float a0, float a1, float a2, float a3, float a4) {
  return fmaxf(fmaxf(fmaxf(a0, a1), fmaxf(a2, a3)), a4);
}

__device__ __forceinline__ unsigned bf16bits(float x) {
  unsigned u = __float_as_uint(x);
  return (u + 0x7fffu + ((u >> 16) & 1u)) >> 16;  // RTNE
}

// packed bf16 pair via HW cvt (RTNE)
__device__ __forceinline__ unsigned cvtpk(float a, float b) {
  unsigned r;
  asm("v_cvt_pk_bf16_f32 %0, %1, %2" : "=v"(r) : "v"(a), "v"(b));
  return r;
}

// swizzled column for the u32 LDS tile (16 cols/row)
__device__ __forceinline__ int swcol(int row, int e) {
  return (e + 11 * (row >> 3) + (row & 7)) & 15;
}

// in-block param prep (race-free: disjoint tid ranges), writes LDS p[]
__device__ void prep_params(float* __restrict__ p,
                            const float* __restrict__ means, const float* __restrict__ lv,
                            const float* __restrict__ linit, const float* __restrict__ tbias,
                            const float* __restrict__ W1g, const float* __restrict__ b1g,
                            const float* __restrict__ W2g, const float* __restrict__ b2g) {
  const int tid = threadIdx.x;  // 256
  if (tid < 80) {
    const float iv = __expf(-lv[tid]);
    p[L_QA + tid] = -0.5f * kL2E * iv;
    p[L_QB + tid] = kL2E * means[tid] * iv;
  }
  if (tid >= 80 && tid < 85) {
    const int s = tid - 80;
    float acc = 0.f;
#pragma unroll
    for (int d = 0; d < 16; ++d) {
      const float lvv = lv[s * 16 + d], mm = means[s * 16 + d];
      acc += lvv + mm * mm * __expf(-lvv);
    }
    p[L_QC + s] = -0.5f * kL2E * (29.406033062549525f + acc);  // 16*ln(2pi)+...
    const float l0 = linit[0], l1 = linit[1], l2 = linit[2], l3 = linit[3],
                l4 = linit[4];
    const float m = max5(l0, l1, l2, l3, l4);
    const float se = __expf(l0 - m) + __expf(l1 - m) + __expf(l2 - m) +
                     __expf(l3 - m) + __expf(l4 - m);
    p[L_LN + s] = kL2E * (linit[s] - (m + __logf(se)));
  }
  if (tid < 100) {  // W1H: half2 pairs of (2/ln2)*W1
    const int i = tid / 20, rem = tid - i * 20, h = rem >> 1, part = rem & 1;
    const int base = (i * 10 + h) * 4 + part * 2;
    p[L_W1H + tid] = __uint_as_float(pkh((2.0f * kL2E) * W1g[base],
                                         (2.0f * kL2E) * W1g[base + 1]));
  }
  if (tid < 60) {  // B1 rows of 12
    const int r = tid / 12, h = tid - r * 12;
    p[L_B1 + tid] = (h < 10) ? (2.0f * kL2E) * b1g[r * 10 + h] : 0.f;
  }
  if (tid < 200) {  // W2H rows of 8
    const int r = tid >> 3, s = tid & 7;
    float v = 0.f;
    if (s < 5) {
      v = __uint_as_float(pkh(-2.0f * kL2E * W2g[r * 10 + 2 * s],
                              -2.0f * kL2E * W2g[r * 10 + 2 * s + 1]));
    } else if (s == 5) {
      float sw = 0.f;
#pragma unroll
      for (int hh = 0; hh < 10; ++hh) sw += W2g[r * 10 + hh];
      v = kL2E * (b2g[r] + tbias[r] + sw);
    }
    p[L_W2H + tid] = v;
  }
}

// E_t = softmax(logits) * diag(exp2(le - c)); f32 emission, f16-dot2 MLP.
__device__ __forceinline__ void buildE(const float* __restrict__ obs,
                                       const float* __restrict__ feat,
                                       const float* __restrict__ p,
                                       size_t t, float E[25], float& c) {
  float o[16], o2[16];
  {
    const float4* o4 = reinterpret_cast<const float4*>(obs + t * kD);
    const float4 v0 = o4[0], v1 = o4[1], v2 = o4[2], v3 = o4[3];
    o[0] = v0.x; o[1] = v0.y; o[2] = v0.z; o[3] = v0.w;
    o[4] = v1.x; o[5] = v1.y; o[6] = v1.z; o[7] = v1.w;
    o[8] = v2.x; o[9] = v2.y; o[10] = v2.z; o[11] = v2.w;
    o[12] = v3.x; o[13] = v3.y; o[14] = v3.z; o[15] = v3.w;
  }
#pragma unroll
  for (int d = 0; d < 16; ++d) o2[d] = o[d] * o[d];
  float le[5];
#pragma unroll
  for (int s = 0; s < 5; ++s) {
    float acc = p[L_QC + s];
#pragma unroll
    for (int dq = 0; dq < 4; ++dq) {
      const float4 qa = *reinterpret_cast<const float4*>(p + L_QA + s * 16 + dq * 4);
      const float4 qb = *reinterpret_cast<const float4*>(p + L_QB + s * 16 + dq * 4);
      acc = fmaf(o2[dq * 4 + 0], qa.x, acc); acc = fmaf(o[dq * 4 + 0], qb.x, acc);
      acc = fmaf(o2[dq * 4 + 1], qa.y, acc); acc = fmaf(o[dq * 4 + 1], qb.y, acc);
      acc = fmaf(o2[dq * 4 + 2], qa.z, acc); acc = fmaf(o[dq * 4 + 2], qb.z, acc);
      acc = fmaf(o2[dq * 4 + 3], qa.w, acc); acc = fmaf(o[dq * 4 + 3], qb.w, acc);
    }
    le[s] = acc;
  }
  c = max5(le[0], le[1], le[2], le[3], le[4]);
  float eml[5];
#pragma unroll
  for (int j = 0; j < 5; ++j) eml[j] = ex2(le[j] - c);
  const float4 f = *reinterpret_cast<const float4*>(feat + t * 4);
  const unsigned f01 = pkh(f.x, f.y), f23 = pkh(f.z, f.w);
#pragma unroll
  for (int i = 0; i < 5; ++i) {
    const float4 bA = *reinterpret_cast<const float4*>(p + L_B1 + i * 12);
    const float4 bB = *reinterpret_cast<const float4*>(p + L_B1 + i * 12 + 4);
    const float2 bC = *reinterpret_cast<const float2*>(p + L_B1 + i * 12 + 8);
    const uint4 wa = *reinterpret_cast<const uint4*>(p + L_W1H + i * 20);
    const uint4 wb = *reinterpret_cast<const uint4*>(p + L_W1H + i * 20 + 4);
    const uint4 wc = *reinterpret_cast<const uint4*>(p + L_W1H + i * 20 + 8);
    const uint4 wd = *reinterpret_cast<const uint4*>(p + L_W1H + i * 20 + 12);
    const uint4 we = *reinterpret_cast<const uint4*>(p + L_W1H + i * 20 + 16);
    // r = rcp(exp(2z)+1); tanh = 1-2r folded into W2'
    const float r0 = __builtin_amdgcn_rcpf(ex2(fdot2u(wa.y, f23, fdot2u(wa.x, f01, bA.x))) + 1.f);
    const float r1 = __builtin_amdgcn_rcpf(ex2(fdot2u(wa.w, f23, fdot2u(wa.z, f01, bA.y))) + 1.f);
    const float r2 = __builtin_amdgcn_rcpf(ex2(fdot2u(wb.y, f23, fdot2u(wb.x, f01, bA.z))) + 1.f);
    const float r3 = __builtin_amdgcn_rcpf(ex2(fdot2u(wb.w, f23, fdot2u(wb.z, f01, bA.w))) + 1.f);
    const float r4 = __builtin_amdgcn_rcpf(ex2(fdot2u(wc.y, f23, fdot2u(wc.x, f01, bB.x))) + 1.f);
    const float r5 = __builtin_amdgcn_rcpf(ex2(fdot2u(wc.w, f23, fdot2u(wc.z, f01, bB.y))) + 1.f);
    const float r6 = __builtin_amdgcn_rcpf(ex2(fdot2u(wd.y, f23, fdot2u(wd.x, f01, bB.z))) + 1.f);
    const float r7 = __builtin_amdgcn_rcpf(ex2(fdot2u(wd.w, f23, fdot2u(wd.z, f01, bB.w))) + 1.f);
    const float r8 = __builtin_amdgcn_rcpf(ex2(fdot2u(we.y, f23, fdot2u(we.x, f01, bC.x))) + 1.f);
    const float r9 = __builtin_amdgcn_rcpf(ex2(fdot2u(we.w, f23, fdot2u(we.z, f01, bC.y))) + 1.f);
    const unsigned h01 = pkh(r0, r1), h23 = pkh(r2, r3), h45 = pkh(r4, r5),
                   h67 = pkh(r6, r7), h89 = pkh(r8, r9);
    float eg[5], se = 0.f;
#pragma unroll
    for (int j = 0; j < 5; ++j) {
      const uint4 v = *reinterpret_cast<const uint4*>(p + L_W2H + (i * 5 + j) * 8);
      const uint2 v2 = *reinterpret_cast<const uint2*>(p + L_W2H + (i * 5 + j) * 8 + 4);
      float acc = __uint_as_float(v2.y);
      acc = fdot2u(v.x, h01, acc);
      acc = fdot2u(v.y, h23, acc);
      acc = fdot2u(v.z, h45, acc);
      acc = fdot2u(v.w, h67, acc);
      acc = fdot2u(v2.x, h89, acc);
      eg[j] = ex2(acc);
      se += eg[j];
    }
    const float rs = __builtin_amdgcn_rcpf(se);
#pragma unroll
    for (int j = 0; j < 5; ++j) E[i * 5 + j] = eg[j] * rs * eml[j];
  }
}

// t=0 pseudo-record: all rows = linear alpha0 (log2-scaled by c)
__device__ __forceinline__ void buildE0(const float* __restrict__ obs,
                                        const float* __restrict__ p, int b,
                                        float E[25], float& c) {
  float o[16], o2[16];
  {
    const float4* o4 = reinterpret_cast<const float4*>(obs + (size_t)b * kT * kD);
    const float4 v0 = o4[0], v1 = o4[1], v2 = o4[2], v3 = o4[3];
    o[0] = v0.x; o[1] = v0.y; o[2] = v0.z; o[3] = v0.w;
    o[4] = v1.x; o[5] = v1.y; o[6] = v1.z; o[7] = v1.w;
    o[8] = v2.x; o[9] = v2.y; o[10] = v2.z; o[11] = v2.w;
    o[12] = v3.x; o[13] = v3.y; o[14] = v3.z; o[15] = v3.w;
  }
#pragma unroll
  for (int d = 0; d < 16; ++d) o2[d] = o[d] * o[d];
  float v[5];
#pragma unroll
  for (int s = 0; s < 5; ++s) {
    float acc = p[L_QC + s];
#pragma unroll
    for (int dq = 0; dq < 4; ++dq) {
      const float4 qa = *reinterpret_cast<const float4*>(p + L_QA + s * 16 + dq * 4);
      const float4 qb = *reinterpret_cast<const float4*>(p + L_QB + s * 16 + dq * 4);
      acc = fmaf(o2[dq * 4 + 0], qa.x, acc); acc = fmaf(o[dq * 4 + 0], qb.x, acc);
      acc = fmaf(o2[dq * 4 + 1], qa.y, acc); acc = fmaf(o[dq * 4 + 1], qb.y, acc);
      acc = fmaf(o2[dq * 4 + 2], qa.z, acc); acc = fmaf(o[dq * 4 + 2], qb.z, acc);
      acc = fmaf(o2[dq * 4 + 3], qa.w, acc); acc = fmaf(o[dq * 4 + 3], qb.w, acc);
    }
    v[s] = acc + p[L_LN + s];
  }
  c = max5(v[0], v[1], v[2], v[3], v[4]);
  float e5[5];
#pragma unroll
  for (int j = 0; j < 5; ++j) e5[j] = 0.2f * ex2(v[j] - c);
#pragma unroll
  for (int i = 0; i < 5; ++i)
#pragma unroll
    for (int j = 0; j < 5; ++j) E[i * 5 + j] = e5[j];
}

__global__ __launch_bounds__(kTile, 4) void k_build(
    const float* __restrict__ obs, const float* __restrict__ feat,
    const float* __restrict__ means, const float* __restrict__ lv,
    const float* __restrict__ linit, const float* __restrict__ tbias,
    const float* __restrict__ W1g, const float* __restrict__ b1g,
    const float* __restrict__ W2g, const float* __restrict__ b2g,
    float* __restrict__ Rg, uint4* __restrict__ e0, uint4* __restrict__ e1,
    uint4* __restrict__ e2, uint2* __restrict__ e3) {
  __shared__ __align__(16) float p[P_TOT];
  __shared__ unsigned sw[kTile * 16];  // 16 KB, bf16-packed E rows (14 words)
  prep_params(p, means, lv, linit, tbias, W1g, b1g, W2g, b2g);
  __syncthreads();
  const int b = blockIdx.y, tile = blockIdx.x, tid = threadIdx.x;
  const int t = tile * kTile + tid;
  const size_t gt = (size_t)b * kT + t;
  {
    float E[25], c;
    if (t == 0) buildE0(obs, p, b, E, c);
    else buildE(obs, feat, p, gt, E, c);
    unsigned w[14];
    w[0] = cvtpk(E[0], E[1]);   w[1] = cvtpk(E[2], E[3]);
    w[2] = cvtpk(E[4], E[5]);   w[3] = cvtpk(E[6], E[7]);
    w[4] = cvtpk(E[8], E[9]);   w[5] = cvtpk(E[10], E[11]);
    w[6] = cvtpk(E[12], E[13]); w[7] = cvtpk(E[14], E[15]);
    w[8] = cvtpk(E[16], E[17]); w[9] = cvtpk(E[18], E[19]);
    w[10] = cvtpk(E[20], E[21]); w[11] = cvtpk(E[22], E[23]);
    {
      const unsigned cb = __float_as_uint(c);
      w[12] = bf16bits(E[24]) | (cb << 16);
      w[13] = cb >> 16;
    }
    e0[gt] = make_uint4(w[0], w[1], w[2], w[3]);
    e1[gt] = make_uint4(w[4], w[5], w[6], w[7]);
    e2[gt] = make_uint4(w[8], w[9], w[10], w[11]);
    e3[gt] = make_uint2(w[12], w[13]);
    const int base = tid * 16;
#pragma unroll
    for (int e = 0; e < 14; ++e) sw[base + swcol(tid, e)] = w[e];
  }
  __syncthreads();
  // row-parallel fold: 8 lanes per chunk, lane ri owns row ri (ri<5 active)
  const int chunk = tid >> 3, ri = tid & 7;
  float R[5], sc;
  {
    const int base = (chunk * 8) * 16, cb = 11 * chunk;  // row&7 = 0
#pragma unroll
    for (int m = 0; m < 5; ++m) {
      const int sl = ri * 5 + m, widx = sl >> 1;
      const unsigned d = sw[base + ((widx + cb) & 15)];
      R[m] = __uint_as_float((sl & 1) ? (d & 0xffff0000u) : (d << 16));
    }
    const unsigned d12 = sw[base + ((12 + cb) & 15)];
    const unsigned d13 = sw[base + ((13 + cb) & 15)];
    sc = __uint_as_float((d12 >> 16) | (d13 << 16));
  }
#pragma unroll 1
  for (int k = 1; k < 8; ++k) {
    const int base = (chunk * 8 + k) * 16, cb = 11 * chunk + k;
    unsigned d[14];
#pragma unroll
    for (int e = 0; e < 14; ++e) d[e] = sw[base + ((e + cb) & 15)];
    float Ek[25];
#pragma unroll
    for (int q = 0; q < 12; ++q) {
      Ek[2 * q]     = __uint_as_float(d[q] << 16);
      Ek[2 * q + 1] = __uint_as_float(d[q] & 0xffff0000u);
    }
    Ek[24] = __uint_as_float(d[12] << 16);
    sc += __uint_as_float((d[12] >> 16) | (d[13] << 16));
    float nR[5];
#pragma unroll
    for (int j = 0; j < 5; ++j) {
      float acc = R[0] * Ek[j];
      acc = fmaf(R[1], Ek[5 + j], acc);
      acc = fmaf(R[2], Ek[10 + j], acc);
      acc = fmaf(R[3], Ek[15 + j], acc);
      acc = fmaf(R[4], Ek[20 + j], acc);
      nR[j] = acc;
    }
#pragma unroll
    for (int j = 0; j < 5; ++j) R[j] = nR[j];
    if ((k & 1) == 0 || k == 7) {  // rescale at k=2,4,6,7
      float rm = (ri < 5) ? max5(R[0], R[1], R[2], R[3], R[4]) : 0.f;
      rm = fmaxf(rm, __shfl_xor(rm, 1, 8));
      rm = fmaxf(rm, __shfl_xor(rm, 2, 8));
      rm = fmaxf(rm, __shfl_xor(rm, 4, 8));
      rm = fmaxf(rm, 1e-30f);
      const float r = __builtin_amdgcn_rcpf(rm);
#pragma unroll
      for (int j = 0; j < 5; ++j) R[j] *= r;
      sc += lg2(rm);
    }
  }
  if (ri < 5) {
    float* outr = Rg + ((size_t)b * kNC + tile * kCPT + chunk) * 28 + ri * 5;
#pragma unroll
    for (int m = 0; m < 5; ++m) outr[m] = R[m];
    if (ri == 0) outr[25] = sc;
  }
}

// ---------- scan helpers (array forms proven fine in these kernels) ----------

__device__ __forceinline__ void matmat5(float R[25], const float E[25]) {
#pragma unroll
  for (int i = 0; i < 5; ++i) {
    const float r0 = R[i * 5 + 0], r1 = R[i * 5 + 1], r2 = R[i * 5 + 2];
    const float r3 = R[i * 5 + 3], r4 = R[i * 5 + 4];
#pragma unroll
    for (int j = 0; j < 5; ++j) {
      float acc = r0 * E[j];
      acc = fmaf(r1, E[5 + j], acc);
      acc = fmaf(r2, E[10 + j], acc);
      acc = fmaf(r3, E[15 + j], acc);
      acc = fmaf(r4, E[20 + j], acc);
      R[i * 5 + j] = acc;
    }
  }
}

__device__ __forceinline__ void rescale25a(float R[25], float& sc) {
  float m = R[0];
#pragma unroll
  for (int e = 1; e < 25; ++e) m = fmaxf(m, R[e]);
  m = fmaxf(m, 1e-30f);
  const float r = __builtin_amdgcn_rcpf(m);
#pragma unroll
  for (int e = 0; e < 25; ++e) R[e] *= r;
  sc += lg2(m);
}

__device__ __forceinline__ void vecmat5(float a[5], const float M[25]) {
  float o[5];
#pragma unroll
  for (int j = 0; j < 5; ++j) {
    float acc = a[0] * M[j];
    acc = fmaf(a[1], M[5 + j], acc);
    acc = fmaf(a[2], M[10 + j], acc);
    acc = fmaf(a[3], M[15 + j], acc);
    acc = fmaf(a[4], M[20 + j], acc);
    o[j] = acc;
  }
#pragma unroll
  for (int j = 0; j < 5; ++j) a[j] = o[j];
}

__device__ __forceinline__ void rescale5(float a[5], float& ls) {
  const float m = fmaxf(max5(a[0], a[1], a[2], a[3], a[4]), 1e-30f);
  const float r = __builtin_amdgcn_rcpf(m);
#pragma unroll
  for (int j = 0; j < 5; ++j) a[j] *= r;
  ls += lg2(m);
}

// one block per b: group products, group scan (LL), within-group scan (start)
__global__ __launch_bounds__(256) void k_scan(const float* __restrict__ Rg,
                                              float* __restrict__ start,
                                              float* __restrict__ out) {
  __shared__ float sR[kNC * 32];  // 64 KB, swizzled: col=(rec+(rec>>4)+e)&31
  __shared__ float sP[kNG * 28];
  __shared__ float sA[kNG * 8];
  const int b = blockIdx.x, tid = threadIdx.x;
#pragma unroll
  for (int r = 0; r < 2; ++r) {
    const int rec = r * 256 + tid;
    const float4* src = reinterpret_cast<const float4*>(Rg + ((size_t)b * kNC + rec) * 28);
    float4 q[7];
#pragma unroll
    for (int i = 0; i < 7; ++i) q[i] = src[i];
    const float* v = reinterpret_cast<const float*>(q);
    const int base = rec * 32, off = rec + (rec >> 4);
#pragma unroll
    for (int e = 0; e < 26; ++e) sR[base + ((off + e) & 31)] = v[e];
  }
  __syncthreads();
  if (tid < kNG) {
    const int g = tid;
    float P[25], psc;
    {
      const int rec = g * kG, base = rec * 32, off = rec + (rec >> 4);
#pragma unroll
      for (int e = 0; e < 25; ++e) P[e] = sR[base + ((off + e) & 31)];
      psc = sR[base + ((off + 25) & 31)];
    }
#pragma unroll 1
    for (int k = 1; k < kG; ++k) {
      const int rec = g * kG + k, base = rec * 32, off = rec + (rec >> 4);
      float M[25];
#pragma unroll
      for (int e = 0; e < 25; ++e) M[e] = sR[base + ((off + e) & 31)];
      psc += sR[base + ((off + 25) & 31)];
      matmat5(P, M);
      if (k & 1) rescale25a(P, psc);
    }
#pragma unroll
    for (int e = 0; e < 25; ++e) sP[g * 28 + e] = P[e];
    sP[g * 28 + 25] = psc;
  }
  __syncthreads();
  if (tid == 0) {
    float a[5] = {1.f, 1.f, 1.f, 1.f, 1.f};
    float ls = 0.f;
#pragma unroll 1
    for (int g = 0; g < kNG; ++g) {
#pragma unroll
      for (int s = 0; s < 5; ++s) sA[g * 8 + s] = a[s];
      sA[g * 8 + 5] = ls;
      float M[25];
#pragma unroll
      for (int e = 0; e < 25; ++e) M[e] = sP[g * 28 + e];
      vecmat5(a, M);
      ls += sP[g * 28 + 25];
      rescale5(a, ls);
    }
    out[b] = (lg2(a[0] + a[1] + a[2] + a[3] + a[4]) + ls) * kLn2;
  }
  __syncthreads();
  if (tid < kNG) {
    const int g = tid;
    float a[5], ls;
#pragma unroll
    for (int s = 0; s < 5; ++s) a[s] = sA[g * 8 + s];
    ls = sA[g * 8 + 5];
#pragma unroll 1
    for (int k = 0; k < kG; ++k) {
      const int cc = g * kG + k;
      float* st = start + ((size_t)b * kNC + cc) * 8;
      reinterpret_cast<float4*>(st)[0] = make_float4(a[0], a[1], a[2], a[3]);
      reinterpret_cast<float4*>(st)[1] = make_float4(a[4], ls, 0.f, 0.f);
      const int base = cc * 32, off = cc + (cc >> 4);
      float M[25];
#pragma unroll
      for (int e = 0; e < 25; ++e) M[e] = sR[base + ((off + e) & 31)];
      ls += sR[base + ((off + 25) & 31)];
      vecmat5(a, M);
      rescale5(a, ls);
    }
  }
}

// stream bf16 E records (SoA); one lane per chunk (8 steps)
__global__ __launch_bounds__(256) void k_alpha_a(const uint4* __restrict__ e0,
                                                 const uint4* __restrict__ e1,
                                                 const uint4* __restrict__ e2,
                                                 const uint2* __restrict__ e3,
                                                 const float* __restrict__ start,
                                                 float* __restrict__ outp) {
  const int gc = blockIdx.x * 256 + threadIdx.x;  // kB*kNC
  const int b = gc >> 9, cc = gc & (kNC - 1);
  const float* st = start + (size_t)gc * 8;
  const float4 s0 = reinterpret_cast<const float4*>(st)[0];
  const float4 s1 = reinterpret_cast<const float4*>(st)[1];
  float a[5] = {s0.x, s0.y, s0.z, s0.w, s1.x};
  float ls = s1.y;
  float ov[40];
  const size_t tb = (size_t)b * kT + (size_t)cc * kC;
#pragma unroll
  for (int k = 0; k < 8; ++k) {
    const uint4 q0 = e0[tb + k], q1 = e1[tb + k], q2 = e2[tb + k];
    const uint2 q3 = e3[tb + k];
    unsigned d[14] = {q0.x, q0.y, q0.z, q0.w, q1.x, q1.y, q1.z, q1.w,
                      q2.x, q2.y, q2.z, q2.w, q3.x, q3.y};
    float E[25];
#pragma unroll
    for (int q = 0; q < 12; ++q) {
      E[2 * q]     = __uint_as_float(d[q] << 16);
      E[2 * q + 1] = __uint_as_float(d[q] & 0xffff0000u);
    }
    E[24] = __uint_as_float(d[12] << 16);
    const float cst = __uint_as_float((d[12] >> 16) | (d[13] << 16));
    float o[5];
#pragma unroll
    for (int j = 0; j < 5; ++j) {
      float acc = a[0] * E[j];
      acc = fmaf(a[1], E[5 + j], acc);
      acc = fmaf(a[2], E[10 + j], acc);
      acc = fmaf(a[3], E[15 + j], acc);
      acc = fmaf(a[4], E[20 + j], acc);
      o[j] = acc;
    }
    ls += cst;
    float L[5];
#pragma unroll
    for (int j = 0; j < 5; ++j) L[j] = lg2(o[j]);
#pragma unroll
    for (int j = 0; j < 5; ++j) ov[k * 5 + j] = (L[j] + ls) * kLn2;
    const float lm = max5(L[0], L[1], L[2], L[3], L[4]);
    const float m = fmaxf(max5(o[0], o[1], o[2], o[3], o[4]), 1e-30f);
    const float r = __builtin_amdgcn_rcpf(m);
#pragma unroll
    for (int j = 0; j < 5; ++j) a[j] = o[j] * r;
    ls += lm;
  }
  float4* w = reinterpret_cast<float4*>(outp + kB + tb * kS);
#pragma unroll
  for (int q = 0; q < 10; ++q)
    w[q] = make_float4(ov[q * 4], ov[q * 4 + 1], ov[q * 4 + 2], ov[q * 4 + 3]);
}

}  // namespace

extern "C" void kernel_launch(void* const* d_in, const int* in_sizes, int n_in,
                              void* d_out, int out_size, void* d_ws, size_t ws_size,
                              hipStream_t stream) {
  (void)in_sizes; (void)n_in; (void)out_size; (void)ws_size;
  const float* obs   = (const float*)d_in[0];
  const float* feat  = (const float*)d_in[1];
  const float* means = (const float*)d_in[2];
  const float* lv    = (const float*)d_in[3];
  const float* linit = (const float*)d_in[4];
  const float* tbias = (const float*)d_in[5];
  const float* W1g   = (const float*)d_in[6];
  const float* b1g   = (const float*)d_in[7];
  const float* W2g   = (const float*)d_in[8];
  const float* b2g   = (const float*)d_in[9];
  float* out = (float*)d_out;

  // ws layout (floats): Rg kB*kNC*28 | start kB*kNC*8 | e0,e1,e2 (uint4) | e3 (uint2)
  float* ws    = (float*)d_ws;
  float* Rg    = ws;
  float* start = Rg + (size_t)kB * kNC * 28;
  uint4* e0 = reinterpret_cast<uint4*>(start + (size_t)kB * kNC * 8);
  uint4* e1 = e0 + (size_t)kB * kT;
  uint4* e2 = e1 + (size_t)kB * kT;
  uint2* e3 = reinterpret_cast<uint2*>(e2 + (size_t)kB * kT);

  dim3 gridB(kT / kTile, kB);
  k_build<<<gridB, kTile, 0, stream>>>(obs, feat, means, lv, linit, tbias,
                                       W1g, b1g, W2g, b2g, Rg, e0, e1, e2, e3);
  k_scan<<<kB, 256, 0, stream>>>(Rg, start, out);
  k_alpha_a<<<(kB * kNC) / 256, 256, 0, stream>>>(e0, e1, e2, e3, start, out);
}

// Round 17
// 108.138 us; speedup vs baseline: 1.1458x; 1.1458x over previous
//
#include <hip/hip_runtime.h>
#include <math.h>

// MarketRegimeHMM forward via chunked associative scan — linear semiring,
// base-2 scales.  R16 = exact restore of the R12 optimum (108.4us):
//   bf16-packed swizzled LDS tile in k_build (16KB -> 64% occupancy),
//   row-parallel fold, separate k_prep, AoS 64B wsE, full-chunk k_alpha.
//   R13 (half-chunk alpha, 117.0), R14 (scalar fold, 111.3), and R15
//   (fused prep + SoA wsE, 123.9) all regressed from this configuration —
//   it is a sharp local optimum whose phase balance absorbs perturbation.
//
//   k_prep  : 1 block; params -> vector layout (f32 emission + half2 MLP).
//   k_build : 256 t per block; thread t builds E_t + packs 14 u32; swizzled
//             u32 LDS transpose; 8 lanes/chunk row-parallel fold -> R[b][c].
//   k_scan  : one block per b; 512-record scan -> start[b][c], LL[b].
//   k_alpha : one lane per chunk: stream bf16 E, 25 FMA + 5 log2 per t.

namespace {

constexpr int kS = 5, kD = 16, kB = 256, kT = 4096;
constexpr int kC = 8, kNC = 512;     // chunks per batch element
constexpr int kTile = 256, kCPT = 32;
constexpr int kG = 16, kNG = 32;

constexpr float kL2E = 1.4426950408889634f;  // 1/ln2
constexpr float kLn2 = 0.6931471805599453f;

// param layout (floats), all vector-read aligned:
constexpr int L_QA  = 0;    // 80  -0.5*inv_v/ln2           [s*16+d] float4
constexpr int L_QB  = 80;   // 80  mu*inv_v/ln2             [s*16+d] float4
constexpr int L_QC  = 160;  // 5   -0.5/ln2*(16ln2pi + sum(lv + iv*mu^2)) (pad->168)
constexpr int L_LN  = 168;  // 5   log2_softmax(log_initial) (pad->176)
constexpr int L_W1H = 176;  // 100 half2 pairs of (2/ln2)*W1: [i*20 + h*2 + {01,23}]
constexpr int L_B1  = 276;  // 60  (2/ln2)*b1, rows of 12    f4,f4,f2
constexpr int L_W2H = 336;  // 200 rows of 8: [0..4]=half2 of -2*W2/ln2 pairs,
                            //     [5]=f32 (b2+tb+sum W2)/ln2, [6,7]=0
constexpr int P_TOT = 544;   // staged floats
constexpr int P_RSV = 1024;  // reserved in ws

typedef __fp16 half2_t __attribute__((ext_vector_type(2)));

#if __has_builtin(__builtin_amdgcn_exp2f)
__device__ __forceinline__ float ex2(float x) { return __builtin_amdgcn_exp2f(x); }
#else
__device__ __forceinline__ float ex2(float x) { return exp2f(x); }
#endif
#if __has_builtin(__builtin_amdgcn_logf)
__device__ __forceinline__ float lg2(float x) { return __builtin_amdgcn_logf(x); }
#else
__device__ __forceinline__ float lg2(float x) { return __log2f(x); }
#endif

__device__ __forceinline__ unsigned pkh(float a, float b) {
  return __builtin_bit_cast(unsigned, __builtin_amdgcn_cvt_pkrtz(a, b));
}

#if __has_builtin(__builtin_amdgcn_fdot2)
__device__ __forceinline__ float fdot2u(unsigned w, unsigned x, float acc) {
  return __builtin_amdgcn_fdot2(__builtin_bit_cast(half2_t, w),
                                __builtin_bit_cast(half2_t, x), acc, false);
}
#else
__device__ __forceinline__ float fdot2u(unsigned w, unsigned x, float acc) {
  const half2_t hw = __builtin_bit_cast(half2_t, w);
  const half2_t hx = __builtin_bit_cast(half2_t, x);
  return acc + (float)hw.x * (float)hx.x + (float)hw.y * (float)hx.y;
}
#endif

__device__ __forceinline__ float max5(float a0, float a1, float a2, float a3, float a4) {
  return fmaxf(fmaxf(fmaxf(a0, a1), fmaxf(a2, a3)), a4);
}

__device__ __forceinline__ unsigned bf16bits(float x) {
  unsigned u = __float_as_uint(x);
  return (u + 0x7fffu + ((u >> 16) & 1u)) >> 16;  // RTNE
}

// packed bf16 pair via HW cvt (RTNE)
__device__ __forceinline__ unsigned cvtpk(float a, float b) {
  unsigned r;
  asm("v_cvt_pk_bf16_f32 %0, %1, %2" : "=v"(r) : "v"(a), "v"(b));
  return r;
}

// swizzled column for the u32 LDS tile (16 cols/row):
// fold reads (rows ch*8+k, fixed k): 11*ch distinct mod 16 -> conflict-free.
__device__ __forceinline__ int swcol(int row, int e) {
  return (e + 11 * (row >> 3) + (row & 7)) & 15;
}

__global__ void k_prep(const float* __restrict__ means, const float* __restrict__ lv,
                       const float* __restrict__ linit, const float* __restrict__ tbias,
                       const float* __restrict__ W1g, const float* __restrict__ b1g,
                       const float* __restrict__ W2g, const float* __restrict__ b2g,
                       float* __restrict__ P) {
  const int tid = threadIdx.x;  // 256; all write ranges disjoint
  if (tid < 80) {
    const float iv = __expf(-lv[tid]);
    P[L_QA + tid] = -0.5f * kL2E * iv;
    P[L_QB + tid] = kL2E * means[tid] * iv;
  }
  if (tid >= 80 && tid < 85) {
    const int s = tid - 80;
    float acc = 0.f;
#pragma unroll
    for (int d = 0; d < 16; ++d) {
      const float lvv = lv[s * 16 + d], mm = means[s * 16 + d];
      acc += lvv + mm * mm * __expf(-lvv);
    }
    P[L_QC + s] = -0.5f * kL2E * (29.406033062549525f + acc);  // 16*ln(2pi)+...
    const float l0 = linit[0], l1 = linit[1], l2 = linit[2], l3 = linit[3],
                l4 = linit[4];
    const float m = max5(l0, l1, l2, l3, l4);
    const float se = __expf(l0 - m) + __expf(l1 - m) + __expf(l2 - m) +
                     __expf(l3 - m) + __expf(l4 - m);
    P[L_LN + s] = kL2E * (linit[s] - (m + __logf(se)));
  }
  if (tid < 100) {  // W1H: half2 pairs of (2/ln2)*W1
    const int i = tid / 20, rem = tid - i * 20, h = rem >> 1, part = rem & 1;
    const int base = (i * 10 + h) * 4 + part * 2;
    P[L_W1H + tid] = __uint_as_float(pkh((2.0f * kL2E) * W1g[base],
                                         (2.0f * kL2E) * W1g[base + 1]));
  }
  if (tid < 60) {  // B1 rows of 12
    const int r = tid / 12, h = tid - r * 12;
    P[L_B1 + tid] = (h < 10) ? (2.0f * kL2E) * b1g[r * 10 + h] : 0.f;
  }
  if (tid < 200) {  // W2H rows of 8
    const int r = tid >> 3, s = tid & 7;
    float v = 0.f;
    if (s < 5) {
      v = __uint_as_float(pkh(-2.0f * kL2E * W2g[r * 10 + 2 * s],
                              -2.0f * kL2E * W2g[r * 10 + 2 * s + 1]));
    } else if (s == 5) {
      float sw = 0.f;
#pragma unroll
      for (int hh = 0; hh < 10; ++hh) sw += W2g[r * 10 + hh];
      v = kL2E * (b2g[r] + tbias[r] + sw);
    }
    P[L_W2H + tid] = v;
  }
  if (tid < 3) { P[165 + tid] = 0.f; P[173 + tid] = 0.f; }  // pads
  if (tid < 8) P[536 + tid] = 0.f;
}

// E_t = softmax(logits) * diag(exp2(le - c)); f32 emission, f16-dot2 MLP.
__device__ __forceinline__ void buildE(const float* __restrict__ obs,
                                       const float* __restrict__ feat,
                                       const float* __restrict__ p,
                                       size_t t, float E[25], float& c) {
  float o[16], o2[16];
  {
    const float4* o4 = reinterpret_cast<const float4*>(obs + t * kD);
    const float4 v0 = o4[0], v1 = o4[1], v2 = o4[2], v3 = o4[3];
    o[0] = v0.x; o[1] = v0.y; o[2] = v0.z; o[3] = v0.w;
    o[4] = v1.x; o[5] = v1.y; o[6] = v1.z; o[7] = v1.w;
    o[8] = v2.x; o[9] = v2.y; o[10] = v2.z; o[11] = v2.w;
    o[12] = v3.x; o[13] = v3.y; o[14] = v3.z; o[15] = v3.w;
  }
#pragma unroll
  for (int d = 0; d < 16; ++d) o2[d] = o[d] * o[d];
  float le[5];
#pragma unroll
  for (int s = 0; s < 5; ++s) {
    float acc = p[L_QC + s];
#pragma unroll
    for (int dq = 0; dq < 4; ++dq) {
      const float4 qa = *reinterpret_cast<const float4*>(p + L_QA + s * 16 + dq * 4);
      const float4 qb = *reinterpret_cast<const float4*>(p + L_QB + s * 16 + dq * 4);
      acc = fmaf(o2[dq * 4 + 0], qa.x, acc); acc = fmaf(o[dq * 4 + 0], qb.x, acc);
      acc = fmaf(o2[dq * 4 + 1], qa.y, acc); acc = fmaf(o[dq * 4 + 1], qb.y, acc);
      acc = fmaf(o2[dq * 4 + 2], qa.z, acc); acc = fmaf(o[dq * 4 + 2], qb.z, acc);
      acc = fmaf(o2[dq * 4 + 3], qa.w, acc); acc = fmaf(o[dq * 4 + 3], qb.w, acc);
    }
    le[s] = acc;
  }
  c = max5(le[0], le[1], le[2], le[3], le[4]);
  float eml[5];
#pragma unroll
  for (int j = 0; j < 5; ++j) eml[j] = ex2(le[j] - c);
  const float4 f = *reinterpret_cast<const float4*>(feat + t * 4);
  const unsigned f01 = pkh(f.x, f.y), f23 = pkh(f.z, f.w);
#pragma unroll
  for (int i = 0; i < 5; ++i) {
    const float4 bA = *reinterpret_cast<const float4*>(p + L_B1 + i * 12);
    const float4 bB = *reinterpret_cast<const float4*>(p + L_B1 + i * 12 + 4);
    const float2 bC = *reinterpret_cast<const float2*>(p + L_B1 + i * 12 + 8);
    const uint4 wa = *reinterpret_cast<const uint4*>(p + L_W1H + i * 20);
    const uint4 wb = *reinterpret_cast<const uint4*>(p + L_W1H + i * 20 + 4);
    const uint4 wc = *reinterpret_cast<const uint4*>(p + L_W1H + i * 20 + 8);
    const uint4 wd = *reinterpret_cast<const uint4*>(p + L_W1H + i * 20 + 12);
    const uint4 we = *reinterpret_cast<const uint4*>(p + L_W1H + i * 20 + 16);
    // r = rcp(exp(2z)+1); tanh = 1-2r folded into W2'
    const float r0 = __builtin_amdgcn_rcpf(ex2(fdot2u(wa.y, f23, fdot2u(wa.x, f01, bA.x))) + 1.f);
    const float r1 = __builtin_amdgcn_rcpf(ex2(fdot2u(wa.w, f23, fdot2u(wa.z, f01, bA.y))) + 1.f);
    const float r2 = __builtin_amdgcn_rcpf(ex2(fdot2u(wb.y, f23, fdot2u(wb.x, f01, bA.z))) + 1.f);
    const float r3 = __builtin_amdgcn_rcpf(ex2(fdot2u(wb.w, f23, fdot2u(wb.z, f01, bA.w))) + 1.f);
    const float r4 = __builtin_amdgcn_rcpf(ex2(fdot2u(wc.y, f23, fdot2u(wc.x, f01, bB.x))) + 1.f);
    const float r5 = __builtin_amdgcn_rcpf(ex2(fdot2u(wc.w, f23, fdot2u(wc.z, f01, bB.y))) + 1.f);
    const float r6 = __builtin_amdgcn_rcpf(ex2(fdot2u(wd.y, f23, fdot2u(wd.x, f01, bB.z))) + 1.f);
    const float r7 = __builtin_amdgcn_rcpf(ex2(fdot2u(wd.w, f23, fdot2u(wd.z, f01, bB.w))) + 1.f);
    const float r8 = __builtin_amdgcn_rcpf(ex2(fdot2u(we.y, f23, fdot2u(we.x, f01, bC.x))) + 1.f);
    const float r9 = __builtin_amdgcn_rcpf(ex2(fdot2u(we.w, f23, fdot2u(we.z, f01, bC.y))) + 1.f);
    const unsigned h01 = pkh(r0, r1), h23 = pkh(r2, r3), h45 = pkh(r4, r5),
                   h67 = pkh(r6, r7), h89 = pkh(r8, r9);
    float eg[5], se = 0.f;
#pragma unroll
    for (int j = 0; j < 5; ++j) {
      const uint4 v = *reinterpret_cast<const uint4*>(p + L_W2H + (i * 5 + j) * 8);
      const uint2 v2 = *reinterpret_cast<const uint2*>(p + L_W2H + (i * 5 + j) * 8 + 4);
      float acc = __uint_as_float(v2.y);
      acc = fdot2u(v.x, h01, acc);
      acc = fdot2u(v.y, h23, acc);
      acc = fdot2u(v.z, h45, acc);
      acc = fdot2u(v.w, h67, acc);
      acc = fdot2u(v2.x, h89, acc);
      eg[j] = ex2(acc);
      se += eg[j];
    }
    const float rs = __builtin_amdgcn_rcpf(se);
#pragma unroll
    for (int j = 0; j < 5; ++j) E[i * 5 + j] = eg[j] * rs * eml[j];
  }
}

// t=0 pseudo-record: all rows = linear alpha0 (log2-scaled by c)
__device__ __forceinline__ void buildE0(const float* __restrict__ obs,
                                        const float* __restrict__ p, int b,
                                        float E[25], float& c) {
  float o[16], o2[16];
  {
    const float4* o4 = reinterpret_cast<const float4*>(obs + (size_t)b * kT * kD);
    const float4 v0 = o4[0], v1 = o4[1], v2 = o4[2], v3 = o4[3];
    o[0] = v0.x; o[1] = v0.y; o[2] = v0.z; o[3] = v0.w;
    o[4] = v1.x; o[5] = v1.y; o[6] = v1.z; o[7] = v1.w;
    o[8] = v2.x; o[9] = v2.y; o[10] = v2.z; o[11] = v2.w;
    o[12] = v3.x; o[13] = v3.y; o[14] = v3.z; o[15] = v3.w;
  }
#pragma unroll
  for (int d = 0; d < 16; ++d) o2[d] = o[d] * o[d];
  float v[5];
#pragma unroll
  for (int s = 0; s < 5; ++s) {
    float acc = p[L_QC + s];
#pragma unroll
    for (int dq = 0; dq < 4; ++dq) {
      const float4 qa = *reinterpret_cast<const float4*>(p + L_QA + s * 16 + dq * 4);
      const float4 qb = *reinterpret_cast<const float4*>(p + L_QB + s * 16 + dq * 4);
      acc = fmaf(o2[dq * 4 + 0], qa.x, acc); acc = fmaf(o[dq * 4 + 0], qb.x, acc);
      acc = fmaf(o2[dq * 4 + 1], qa.y, acc); acc = fmaf(o[dq * 4 + 1], qb.y, acc);
      acc = fmaf(o2[dq * 4 + 2], qa.z, acc); acc = fmaf(o[dq * 4 + 2], qb.z, acc);
      acc = fmaf(o2[dq * 4 + 3], qa.w, acc); acc = fmaf(o[dq * 4 + 3], qb.w, acc);
    }
    v[s] = acc + p[L_LN + s];
  }
  c = max5(v[0], v[1], v[2], v[3], v[4]);
  float e5[5];
#pragma unroll
  for (int j = 0; j < 5; ++j) e5[j] = 0.2f * ex2(v[j] - c);
#pragma unroll
  for (int i = 0; i < 5; ++i)
#pragma unroll
    for (int j = 0; j < 5; ++j) E[i * 5 + j] = e5[j];
}

template <bool STORE_E>
__global__ __launch_bounds__(kTile, 4) void k_build(
    const float* __restrict__ obs, const float* __restrict__ feat,
    const float* __restrict__ P, float* __restrict__ Rg,
    uint4* __restrict__ wsE) {
  __shared__ __align__(16) float p[P_TOT];
  __shared__ unsigned sw[kTile * 16];  // 16 KB, bf16-packed E rows (14 words)
  if (threadIdx.x < P_TOT / 4)
    reinterpret_cast<float4*>(p)[threadIdx.x] =
        reinterpret_cast<const float4*>(P)[threadIdx.x];
  __syncthreads();
  const int b = blockIdx.y, tile = blockIdx.x, tid = threadIdx.x;
  const int t = tile * kTile + tid;
  const size_t gt = (size_t)b * kT + t;
  float E[25], c;
  if (t == 0) buildE0(obs, p, b, E, c);
  else buildE(obs, feat, p, gt, E, c);
  unsigned w[14];
  w[0] = cvtpk(E[0], E[1]);   w[1] = cvtpk(E[2], E[3]);
  w[2] = cvtpk(E[4], E[5]);   w[3] = cvtpk(E[6], E[7]);
  w[4] = cvtpk(E[8], E[9]);   w[5] = cvtpk(E[10], E[11]);
  w[6] = cvtpk(E[12], E[13]); w[7] = cvtpk(E[14], E[15]);
  w[8] = cvtpk(E[16], E[17]); w[9] = cvtpk(E[18], E[19]);
  w[10] = cvtpk(E[20], E[21]); w[11] = cvtpk(E[22], E[23]);
  {
    const unsigned cb = __float_as_uint(c);
    w[12] = bf16bits(E[24]) | (cb << 16);
    w[13] = cb >> 16;
  }
  if (STORE_E) {
    uint4* wp = wsE + gt * 4;
    wp[0] = make_uint4(w[0], w[1], w[2], w[3]);
    wp[1] = make_uint4(w[4], w[5], w[6], w[7]);
    wp[2] = make_uint4(w[8], w[9], w[10], w[11]);
    wp[3] = make_uint4(w[12], w[13], 0u, 0u);
  }
  {
    const int base = tid * 16;
#pragma unroll
    for (int e = 0; e < 14; ++e) sw[base + swcol(tid, e)] = w[e];
  }
  __syncthreads();
  // row-parallel fold: 8 lanes per chunk, lane ri owns row ri (ri<5 active)
  const int chunk = tid >> 3, ri = tid & 7;
  float R[5], sc;
  {
    // initial: R = row ri of E at row=chunk*8 (runtime word index + select)
    const int row = chunk * 8, base = row * 16, cb = 11 * chunk;  // row&7 = 0
#pragma unroll
    for (int m = 0; m < 5; ++m) {
      const int sl = ri * 5 + m, widx = sl >> 1;
      const unsigned d = sw[base + ((widx + cb) & 15)];
      R[m] = __uint_as_float((sl & 1) ? (d & 0xffff0000u) : (d << 16));
    }
    const unsigned d12 = sw[base + ((12 + cb) & 15)];
    const unsigned d13 = sw[base + ((13 + cb) & 15)];
    sc = __uint_as_float((d12 >> 16) | (d13 << 16));
  }
#pragma unroll 1
  for (int k = 1; k < 8; ++k) {
    const int row = chunk * 8 + k, base = row * 16, cb = 11 * chunk + k;
    unsigned d[14];
#pragma unroll
    for (int e = 0; e < 14; ++e) d[e] = sw[base + ((e + cb) & 15)];
    float Ek[25];
#pragma unroll
    for (int q = 0; q < 12; ++q) {
      Ek[2 * q]     = __uint_as_float(d[q] << 16);
      Ek[2 * q + 1] = __uint_as_float(d[q] & 0xffff0000u);
    }
    Ek[24] = __uint_as_float(d[12] << 16);
    sc += __uint_as_float((d[12] >> 16) | (d[13] << 16));
    float nR[5];
#pragma unroll
    for (int j = 0; j < 5; ++j) {
      float acc = R[0] * Ek[j];
      acc = fmaf(R[1], Ek[5 + j], acc);
      acc = fmaf(R[2], Ek[10 + j], acc);
      acc = fmaf(R[3], Ek[15 + j], acc);
      acc = fmaf(R[4], Ek[20 + j], acc);
      nR[j] = acc;
    }
#pragma unroll
    for (int j = 0; j < 5; ++j) R[j] = nR[j];
    if ((k & 1) == 0 || k == 7) {  // rescale at k=2,4,6,7
      float rm = (ri < 5) ? max5(R[0], R[1], R[2], R[3], R[4]) : 0.f;
      rm = fmaxf(rm, __shfl_xor(rm, 1, 8));
      rm = fmaxf(rm, __shfl_xor(rm, 2, 8));
      rm = fmaxf(rm, __shfl_xor(rm, 4, 8));
      rm = fmaxf(rm, 1e-30f);
      const float r = __builtin_amdgcn_rcpf(rm);
#pragma unroll
      for (int j = 0; j < 5; ++j) R[j] *= r;
      sc += lg2(rm);
    }
  }
  if (ri < 5) {
    float* outr = Rg + ((size_t)b * kNC + tile * kCPT + chunk) * 28 + ri * 5;
#pragma unroll
    for (int m = 0; m < 5; ++m) outr[m] = R[m];
    if (ri == 0) outr[25] = sc;
  }
}

// ---------- scan helpers (array forms proven fine in these kernels) ----------

__device__ __forceinline__ void matmat5(float R[25], const float E[25]) {
#pragma unroll
  for (int i = 0; i < 5; ++i) {
    const float r0 = R[i * 5 + 0], r1 = R[i * 5 + 1], r2 = R[i * 5 + 2];
    const float r3 = R[i * 5 + 3], r4 = R[i * 5 + 4];
#pragma unroll
    for (int j = 0; j < 5; ++j) {
      float acc = r0 * E[j];
      acc = fmaf(r1, E[5 + j], acc);
      acc = fmaf(r2, E[10 + j], acc);
      acc = fmaf(r3, E[15 + j], acc);
      acc = fmaf(r4, E[20 + j], acc);
      R[i * 5 + j] = acc;
    }
  }
}

__device__ __forceinline__ void rescale25a(float R[25], float& sc) {
  float m = R[0];
#pragma unroll
  for (int e = 1; e < 25; ++e) m = fmaxf(m, R[e]);
  m = fmaxf(m, 1e-30f);
  const float r = __builtin_amdgcn_rcpf(m);
#pragma unroll
  for (int e = 0; e < 25; ++e) R[e] *= r;
  sc += lg2(m);
}

__device__ __forceinline__ void vecmat5(float a[5], const float M[25]) {
  float o[5];
#pragma unroll
  for (int j = 0; j < 5; ++j) {
    float acc = a[0] * M[j];
    acc = fmaf(a[1], M[5 + j], acc);
    acc = fmaf(a[2], M[10 + j], acc);
    acc = fmaf(a[3], M[15 + j], acc);
    acc = fmaf(a[4], M[20 + j], acc);
    o[j] = acc;
  }
#pragma unroll
  for (int j = 0; j < 5; ++j) a[j] = o[j];
}

__device__ __forceinline__ void rescale5(float a[5], float& ls) {
  const float m = fmaxf(max5(a[0], a[1], a[2], a[3], a[4]), 1e-30f);
  const float r = __builtin_amdgcn_rcpf(m);
#pragma unroll
  for (int j = 0; j < 5; ++j) a[j] *= r;
  ls += lg2(m);
}

// one block per b: group products, group scan (LL), within-group scan (start)
__global__ __launch_bounds__(256) void k_scan(const float* __restrict__ Rg,
                                              float* __restrict__ start,
                                              float* __restrict__ out) {
  __shared__ float sR[kNC * 32];  // 64 KB, swizzled: col=(rec+(rec>>4)+e)&31
  __shared__ float sP[kNG * 28];
  __shared__ float sA[kNG * 8];
  const int b = blockIdx.x, tid = threadIdx.x;
#pragma unroll
  for (int r = 0; r < 2; ++r) {
    const int rec = r * 256 + tid;
    const float4* src = reinterpret_cast<const float4*>(Rg + ((size_t)b * kNC + rec) * 28);
    float4 q[7];
#pragma unroll
    for (int i = 0; i < 7; ++i) q[i] = src[i];
    const float* v = reinterpret_cast<const float*>(q);
    const int base = rec * 32, off = rec + (rec >> 4);
#pragma unroll
    for (int e = 0; e < 26; ++e) sR[base + ((off + e) & 31)] = v[e];
  }
  __syncthreads();
  if (tid < kNG) {
    const int g = tid;
    float P[25], psc;
    {
      const int rec = g * kG, base = rec * 32, off = rec + (rec >> 4);
#pragma unroll
      for (int e = 0; e < 25; ++e) P[e] = sR[base + ((off + e) & 31)];
      psc = sR[base + ((off + 25) & 31)];
    }
#pragma unroll 1
    for (int k = 1; k < kG; ++k) {
      const int rec = g * kG + k, base = rec * 32, off = rec + (rec >> 4);
      float M[25];
#pragma unroll
      for (int e = 0; e < 25; ++e) M[e] = sR[base + ((off + e) & 31)];
      psc += sR[base + ((off + 25) & 31)];
      matmat5(P, M);
      if (k & 1) rescale25a(P, psc);
    }
#pragma unroll
    for (int e = 0; e < 25; ++e) sP[g * 28 + e] = P[e];
    sP[g * 28 + 25] = psc;
  }
  __syncthreads();
  if (tid == 0) {
    float a[5] = {1.f, 1.f, 1.f, 1.f, 1.f};
    float ls = 0.f;
#pragma unroll 1
    for (int g = 0; g < kNG; ++g) {
#pragma unroll
      for (int s = 0; s < 5; ++s) sA[g * 8 + s] = a[s];
      sA[g * 8 + 5] = ls;
      float M[25];
#pragma unroll
      for (int e = 0; e < 25; ++e) M[e] = sP[g * 28 + e];
      vecmat5(a, M);
      ls += sP[g * 28 + 25];
      rescale5(a, ls);
    }
    out[b] = (lg2(a[0] + a[1] + a[2] + a[3] + a[4]) + ls) * kLn2;
  }
  __syncthreads();
  if (tid < kNG) {
    const int g = tid;
    float a[5], ls;
#pragma unroll
    for (int s = 0; s < 5; ++s) a[s] = sA[g * 8 + s];
    ls = sA[g * 8 + 5];
#pragma unroll 1
    for (int k = 0; k < kG; ++k) {
      const int cc = g * kG + k;
      float* st = start + ((size_t)b * kNC + cc) * 8;
      reinterpret_cast<float4*>(st)[0] = make_float4(a[0], a[1], a[2], a[3]);
      reinterpret_cast<float4*>(st)[1] = make_float4(a[4], ls, 0.f, 0.f);
      const int base = cc * 32, off = cc + (cc >> 4);
      float M[25];
#pragma unroll
      for (int e = 0; e < 25; ++e) M[e] = sR[base + ((off + e) & 31)];
      ls += sR[base + ((off + 25) & 31)];
      vecmat5(a, M);
      rescale5(a, ls);
    }
  }
}

// stream bf16 E records; one lane per chunk (8 steps)
__global__ __launch_bounds__(256) void k_alpha_a(const uint4* __restrict__ wsE,
                                                 const float* __restrict__ start,
                                                 float* __restrict__ outp) {
  const int gc = blockIdx.x * 256 + threadIdx.x;  // kB*kNC
  const int b = gc >> 9, cc = gc & (kNC - 1);
  const float* st = start + (size_t)gc * 8;
  const float4 s0 = reinterpret_cast<const float4*>(st)[0];
  const float4 s1 = reinterpret_cast<const float4*>(st)[1];
  float a[5] = {s0.x, s0.y, s0.z, s0.w, s1.x};
  float ls = s1.y;
  float ov[40];
  const uint4* ep = wsE + ((size_t)b * kT + (size_t)cc * kC) * 4;
#pragma unroll
  for (int k = 0; k < 8; ++k) {
    uint4 q0 = ep[k * 4], q1 = ep[k * 4 + 1], q2 = ep[k * 4 + 2], q3 = ep[k * 4 + 3];
    unsigned d[14] = {q0.x, q0.y, q0.z, q0.w, q1.x, q1.y, q1.z, q1.w,
                      q2.x, q2.y, q2.z, q2.w, q3.x, q3.y};
    float E[25];
#pragma unroll
    for (int q = 0; q < 12; ++q) {
      E[2 * q]     = __uint_as_float(d[q] << 16);
      E[2 * q + 1] = __uint_as_float(d[q] & 0xffff0000u);
    }
    E[24] = __uint_as_float(d[12] << 16);
    const float cst = __uint_as_float((d[12] >> 16) | (d[13] << 16));
    float o[5];
#pragma unroll
    for (int j = 0; j < 5; ++j) {
      float acc = a[0] * E[j];
      acc = fmaf(a[1], E[5 + j], acc);
      acc = fmaf(a[2], E[10 + j], acc);
      acc = fmaf(a[3], E[15 + j], acc);
      acc = fmaf(a[4], E[20 + j], acc);
      o[j] = acc;
    }
    ls += cst;
    float L[5];
#pragma unroll
    for (int j = 0; j < 5; ++j) L[j] = lg2(o[j]);
#pragma unroll
    for (int j = 0; j < 5; ++j) ov[k * 5 + j] = (L[j] + ls) * kLn2;
    const float lm = max5(L[0], L[1], L[2], L[3], L[4]);
    const float m = fmaxf(max5(o[0], o[1], o[2], o[3], o[4]), 1e-30f);
    const float r = __builtin_amdgcn_rcpf(m);
#pragma unroll
    for (int j = 0; j < 5; ++j) a[j] = o[j] * r;
    ls += lm;
  }
  float4* w = reinterpret_cast<float4*>(outp + kB + ((size_t)b * kT + (size_t)cc * kC) * kS);
#pragma unroll
  for (int q = 0; q < 10; ++q)
    w[q] = make_float4(ov[q * 4], ov[q * 4 + 1], ov[q * 4 + 2], ov[q * 4 + 3]);
}

}  // namespace

extern "C" void kernel_launch(void* const* d_in, const int* in_sizes, int n_in,
                              void* d_out, int out_size, void* d_ws, size_t ws_size,
                              hipStream_t stream) {
  (void)in_sizes; (void)n_in; (void)out_size; (void)ws_size;
  const float* obs   = (const float*)d_in[0];
  const float* feat  = (const float*)d_in[1];
  const float* means = (const float*)d_in[2];
  const float* lv    = (const float*)d_in[3];
  const float* linit = (const float*)d_in[4];
  const float* tbias = (const float*)d_in[5];
  const float* W1g   = (const float*)d_in[6];
  const float* b1g   = (const float*)d_in[7];
  const float* W2g   = (const float*)d_in[8];
  const float* b2g   = (const float*)d_in[9];
  float* out = (float*)d_out;

  // ws layout (floats): P 1024 | Rg kB*kNC*28 | start kB*kNC*8 | wsE (bytes)
  float* P     = (float*)d_ws;
  float* Rg    = P + P_RSV;
  float* start = Rg + (size_t)kB * kNC * 28;
  uint4* wsE   = reinterpret_cast<uint4*>(start + (size_t)kB * kNC * 8);

  k_prep<<<1, 256, 0, stream>>>(means, lv, linit, tbias, W1g, b1g, W2g, b2g, P);
  dim3 gridB(kT / kTile, kB);
  k_build<true><<<gridB, kTile, 0, stream>>>(obs, feat, P, Rg, wsE);
  k_scan<<<kB, 256, 0, stream>>>(Rg, start, out);
  k_alpha_a<<<(kB * kNC) / 256, 256, 0, stream>>>(wsE, start, out);
}